// Round 1
// baseline (267.759 us; speedup 1.0000x reference)
//
#include <hip/hip_runtime.h>
#include <stdint.h>

#define K_NODES 14
#define C_DIM   512
#define OUT_DIM 512
#define N_EDGE  78

typedef float  f32x4  __attribute__((ext_vector_type(4)));
typedef __bf16 bf16x8 __attribute__((ext_vector_type(8)));

__device__ __forceinline__ unsigned short f2bf(float f) {
    unsigned int u = __builtin_bit_cast(unsigned int, f);
    unsigned int r = (u + 0x7fffu + ((u >> 16) & 1u)) >> 16;  // RNE
    return (unsigned short)r;
}

// ---------------- Kernel 1: per-channel stats partial sums -----------------
// gap[n,e,c] = 15*(d_i - d_j), d_k = |x[n,k,c]-x[n,13,c]|, edges = pairs i<j in 0..12
// sum_e gap      = 15 * sum_k (12-2k) d_k
// sum_e gap^2    = 225 * (13*sum d^2 - (sum d)^2)
__global__ __launch_bounds__(512) void stats_partial(
    const float* __restrict__ x, float* __restrict__ part, int n_per_block)
{
    int c  = threadIdx.x;
    int n0 = blockIdx.x * n_per_block;
    float s_sum = 0.f, s_sq = 0.f;
    for (int nn = 0; nn < n_per_block; ++nn) {
        const float* xb = x + (size_t)(n0 + nn) * K_NODES * C_DIM + c;
        float g = xb[13 * C_DIM];
        float S1 = 0.f, S2 = 0.f, Sw = 0.f;
        #pragma unroll
        for (int k = 0; k < 13; ++k) {
            float d = fabsf(xb[k * C_DIM] - g);
            S1 += d; S2 += d * d; Sw += (float)(12 - 2 * k) * d;
        }
        s_sum += 15.f * Sw;
        s_sq  += 225.f * (13.f * S2 - S1 * S1);
    }
    part[(size_t)blockIdx.x * 1024 + c]       = s_sum;
    part[(size_t)blockIdx.x * 1024 + 512 + c] = s_sq;
}

// ---------------- Kernel 2: finalize stats -> u[c], Bconst -----------------
__global__ __launch_bounds__(512) void finalize_stats(
    const float* __restrict__ part, int nblocks, float inv_ne,
    const float* __restrict__ gamma, const float* __restrict__ beta,
    const float* __restrict__ wdir, float* __restrict__ u, float* __restrict__ bconst)
{
    int c = threadIdx.x;
    float s = 0.f, q = 0.f;
    for (int b = 0; b < nblocks; ++b) {
        s += part[(size_t)b * 1024 + c];
        q += part[(size_t)b * 1024 + 512 + c];
    }
    float mean = s * inv_ne;
    float var  = q * inv_ne - mean * mean;
    float sc   = gamma[c] / sqrtf(var + 1e-5f);
    u[c] = sc * wdir[c];
    __shared__ float red[512];
    red[c] = (beta[c] - mean * sc) * wdir[c];
    __syncthreads();
    for (int st = 256; st > 0; st >>= 1) {
        if (c < st) red[c] += red[c + st];
        __syncthreads();
    }
    if (c == 0) *bconst = red[0];
}

// ---------------- Kernel 3: weights fp32 -> bf16 ---------------------------
__global__ __launch_bounds__(256) void conv_w(
    const float* __restrict__ a, const float* __restrict__ b,
    unsigned short* __restrict__ oa, unsigned short* __restrict__ ob)
{
    int i = blockIdx.x * 256 + threadIdx.x;   // 262144 elements each
    oa[i] = f2bf(a[i]);
    ob[i] = f2bf(b[i]);
}

// ---------------- Kernel 4: per-n gates + adjacency + agg ------------------
__global__ __launch_bounds__(512) void fuse_graph(
    const float* __restrict__ x, const float* __restrict__ adj,
    const int* __restrict__ ei, const int* __restrict__ ej,
    const float* __restrict__ u, const float* __restrict__ bconst,
    unsigned short* __restrict__ xbf, unsigned short* __restrict__ aggbf)
{
    __shared__ float lx[K_NODES][C_DIM];
    __shared__ float Dl[13];
    __shared__ float Wl[K_NODES][K_NODES];
    __shared__ float rnorm[K_NODES];
    int n = blockIdx.x, c = threadIdx.x;
    size_t base = (size_t)n * K_NODES * C_DIM;

    #pragma unroll
    for (int k = 0; k < K_NODES; ++k) {
        float v = x[base + k * C_DIM + c];
        lx[k][c] = v;
        xbf[base + k * C_DIM + c] = f2bf(v);
    }
    if (c < 13) Dl[c] = 0.f;
    __syncthreads();

    float g  = lx[13][c];
    float uc = u[c];
    #pragma unroll
    for (int k = 0; k < 13; ++k) {
        float val = fabsf(lx[k][c] - g) * uc;
        #pragma unroll
        for (int off = 32; off > 0; off >>= 1) val += __shfl_down(val, off, 64);
        if ((c & 63) == 0) atomicAdd(&Dl[k], val);
    }
    __syncthreads();

    if (c < K_NODES * K_NODES) ((float*)Wl)[c] = 1.f;
    __syncthreads();
    if (c < N_EDGE) {
        float z = 4.0f * (15.f * (Dl[ei[c]] - Dl[ej[c]]) + *bconst);
        float a = 1.f / (1.f + expf(-z));
        Wl[ei[c]][ej[c]] = 2.f * a;
        Wl[ej[c]][ei[c]] = 2.f * (1.f - a);
    }
    __syncthreads();
    if (c < K_NODES * K_NODES) ((float*)Wl)[c] *= adj[c];
    __syncthreads();
    if (c < K_NODES) {
        float s = 0.f;
        #pragma unroll
        for (int j = 0; j < K_NODES; ++j) s += fabsf(Wl[c][j]);
        rnorm[c] = fmaxf(s, 1e-12f);
    }
    __syncthreads();
    if (c < K_NODES * K_NODES) ((float*)Wl)[c] /= rnorm[c / K_NODES];
    __syncthreads();

    #pragma unroll
    for (int i = 0; i < K_NODES; ++i) {
        float s = 0.f;
        #pragma unroll
        for (int j = 0; j < K_NODES; ++j) s += Wl[i][j] * lx[j][c];
        aggbf[base + i * C_DIM + c] = f2bf(s);
    }
}

// ---------------- Kernel 5: fused GEMM: relu(agg@Wm^T) + x@Wo^T ------------
#define TM 128
#define TN 128
#define BK 32
#define LSTR 40   // LDS row stride in ushorts (padded from 32 -> 2-way banks)

__global__ __launch_bounds__(256) void gemm_fused(
    const unsigned short* __restrict__ Aagg, const unsigned short* __restrict__ Axin,
    const unsigned short* __restrict__ Bwm,  const unsigned short* __restrict__ Bwo,
    float* __restrict__ out)
{
    __shared__ unsigned short lA[TM * LSTR];
    __shared__ unsigned short lB[TN * LSTR];
    int tid  = threadIdx.x;
    int lane = tid & 63;
    int wave = tid >> 6;
    int wr = wave >> 1, wc = wave & 1;
    int bm = blockIdx.x * TM;
    int bn = blockIdx.y * TN;

    f32x4 acc[4][4];
    #pragma unroll
    for (int i = 0; i < 4; ++i)
        #pragma unroll
        for (int j = 0; j < 4; ++j) acc[i][j] = (f32x4){0.f, 0.f, 0.f, 0.f};

    int srow   = tid >> 2;          // 0..63
    int schunk = (tid & 3) * 8;     // ushort offset in the 32-wide k slab
    int lrow   = lane & 15;
    int lkoff  = (lane >> 4) * 8;

    #pragma unroll
    for (int pass = 0; pass < 2; ++pass) {
        const unsigned short* A = pass ? Axin : Aagg;
        const unsigned short* B = pass ? Bwo  : Bwm;
        for (int kb = 0; kb < C_DIM; kb += BK) {
            __syncthreads();
            uint4 va0 = *(const uint4*)(A + (size_t)(bm + srow) * C_DIM + kb + schunk);
            uint4 va1 = *(const uint4*)(A + (size_t)(bm + srow + 64) * C_DIM + kb + schunk);
            uint4 vb0 = *(const uint4*)(B + (size_t)(bn + srow) * C_DIM + kb + schunk);
            uint4 vb1 = *(const uint4*)(B + (size_t)(bn + srow + 64) * C_DIM + kb + schunk);
            *(uint4*)&lA[srow * LSTR + schunk]        = va0;
            *(uint4*)&lA[(srow + 64) * LSTR + schunk] = va1;
            *(uint4*)&lB[srow * LSTR + schunk]        = vb0;
            *(uint4*)&lB[(srow + 64) * LSTR + schunk] = vb1;
            __syncthreads();

            bf16x8 af[4], bfr[4];
            #pragma unroll
            for (int i = 0; i < 4; ++i)
                af[i] = *(const bf16x8*)&lA[(wr * 64 + i * 16 + lrow) * LSTR + lkoff];
            #pragma unroll
            for (int j = 0; j < 4; ++j)
                bfr[j] = *(const bf16x8*)&lB[(wc * 64 + j * 16 + lrow) * LSTR + lkoff];
            #pragma unroll
            for (int i = 0; i < 4; ++i)
                #pragma unroll
                for (int j = 0; j < 4; ++j)
                    acc[i][j] = __builtin_amdgcn_mfma_f32_16x16x32_bf16(
                        af[i], bfr[j], acc[i][j], 0, 0, 0);
        }
        if (pass == 0) {
            #pragma unroll
            for (int i = 0; i < 4; ++i)
                #pragma unroll
                for (int j = 0; j < 4; ++j)
                    #pragma unroll
                    for (int r = 0; r < 4; ++r)
                        acc[i][j][r] = fmaxf(acc[i][j][r], 0.f);
        }
    }

    int orow0 = bm + wr * 64 + (lane >> 4) * 4;
    int ocol0 = bn + wc * 64 + (lane & 15);
    #pragma unroll
    for (int i = 0; i < 4; ++i)
        #pragma unroll
        for (int j = 0; j < 4; ++j)
            #pragma unroll
            for (int r = 0; r < 4; ++r)
                out[(size_t)(orow0 + i * 16 + r) * OUT_DIM + (ocol0 + j * 16)] = acc[i][j][r];
}

extern "C" void kernel_launch(void* const* d_in, const int* in_sizes, int n_in,
                              void* d_out, int out_size, void* d_ws, size_t ws_size,
                              hipStream_t stream)
{
    const float* x     = (const float*)d_in[0];
    const float* adj   = (const float*)d_in[1];
    const int*   ei    = (const int*)d_in[2];
    const int*   ej    = (const int*)d_in[3];
    const float* gamma = (const float*)d_in[4];
    const float* beta  = (const float*)d_in[5];
    const float* wdir  = (const float*)d_in[6];
    const float* Wm    = (const float*)d_in[7];
    const float* Wo    = (const float*)d_in[8];
    float* out = (float*)d_out;

    int N = in_sizes[0] / (K_NODES * C_DIM);   // 2048
    int M = N * K_NODES;                        // 28672

    // workspace layout (floats / bytes)
    float* ws_f   = (float*)d_ws;
    float* u      = ws_f + 1024;               // [512]
    float* bconst = ws_f + 1536;               // [1]
    float* part   = ws_f + 2048;               // [256*1024]
    char*  wsb    = (char*)d_ws;
    size_t off    = (size_t)(2048 + 256 * 1024) * sizeof(float);   // 1,056,768
    unsigned short* wmbf  = (unsigned short*)(wsb + off);               off += (size_t)OUT_DIM * C_DIM * 2;
    unsigned short* wobf  = (unsigned short*)(wsb + off);               off += (size_t)OUT_DIM * C_DIM * 2;
    unsigned short* xbf   = (unsigned short*)(wsb + off);               off += (size_t)M * C_DIM * 2;
    unsigned short* aggbf = (unsigned short*)(wsb + off);               // + M*C*2 -> ~61 MB total

    const int stats_blocks = 256;
    int n_per_block = N / stats_blocks;
    float inv_ne = 1.0f / ((float)N * (float)N_EDGE);

    hipLaunchKernelGGL(stats_partial, dim3(stats_blocks), dim3(512), 0, stream,
                       x, part, n_per_block);
    hipLaunchKernelGGL(finalize_stats, dim3(1), dim3(512), 0, stream,
                       part, stats_blocks, inv_ne, gamma, beta, wdir, u, bconst);
    hipLaunchKernelGGL(conv_w, dim3((OUT_DIM * C_DIM) / 256), dim3(256), 0, stream,
                       Wm, Wo, wmbf, wobf);
    hipLaunchKernelGGL(fuse_graph, dim3(N), dim3(512), 0, stream,
                       x, adj, ei, ej, u, bconst, xbf, aggbf);
    hipLaunchKernelGGL(gemm_fused, dim3(M / TM, OUT_DIM / TN), dim3(256), 0, stream,
                       aggbf, xbf, wmbf, wobf, out);
}

// Round 2
// 215.968 us; speedup vs baseline: 1.2398x; 1.2398x over previous
//
#include <hip/hip_runtime.h>
#include <stdint.h>

#define K_NODES 14
#define C_DIM   512
#define OUT_DIM 512
#define N_EDGE  78

typedef float  f32x4  __attribute__((ext_vector_type(4)));
typedef __bf16 bf16x8 __attribute__((ext_vector_type(8)));

__device__ __forceinline__ unsigned short f2bf(float f) {
    unsigned int u = __builtin_bit_cast(unsigned int, f);
    unsigned int r = (u + 0x7fffu + ((u >> 16) & 1u)) >> 16;  // RNE
    return (unsigned short)r;
}
__device__ __forceinline__ float bf2f(unsigned short s) {
    return __builtin_bit_cast(float, (unsigned int)s << 16);
}

// async 16B global -> LDS (LDS dest must be wave-uniform base; HW adds lane*16)
__device__ __forceinline__ void async16(const void* g, void* l) {
    __builtin_amdgcn_global_load_lds(
        (const __attribute__((address_space(1))) unsigned int*)g,
        (__attribute__((address_space(3))) unsigned int*)l, 16, 0, 0);
}

// ---------------- Kernel 1: per-channel stats partials + x -> bf16 ---------
// d_k = |x[n,k,c]-x[n,13,c]|  (k=0..12)
// sum_e gap   = 15 * sum_k (12-2k) d_k ;  sum_e gap^2 = 225*(13*sum d^2 - (sum d)^2)
__global__ __launch_bounds__(512) void stats_partial(
    const float* __restrict__ x, float* __restrict__ part,
    unsigned short* __restrict__ xbf, int n_per_block)
{
    int c  = threadIdx.x;
    int n0 = blockIdx.x * n_per_block;
    float s_sum = 0.f, s_sq = 0.f;
    for (int nn = 0; nn < n_per_block; ++nn) {
        size_t base = (size_t)(n0 + nn) * K_NODES * C_DIM + c;
        const float* xb = x + base;
        unsigned short* xo = xbf + base;
        float g = xb[13 * C_DIM];
        xo[13 * C_DIM] = f2bf(g);
        float S1 = 0.f, S2 = 0.f, Sw = 0.f;
        #pragma unroll
        for (int k = 0; k < 13; ++k) {
            float v = xb[k * C_DIM];
            xo[k * C_DIM] = f2bf(v);
            float d = fabsf(v - g);
            S1 += d; S2 += d * d; Sw += (float)(12 - 2 * k) * d;
        }
        s_sum += 15.f * Sw;
        s_sq  += 225.f * (13.f * S2 - S1 * S1);
    }
    part[(size_t)blockIdx.x * 1024 + c]       = s_sum;
    part[(size_t)blockIdx.x * 1024 + 512 + c] = s_sq;
}

// ---------------- Kernel 2: finalize stats -> u[c], Bconst -----------------
__global__ __launch_bounds__(1024) void finalize_stats(
    const float* __restrict__ part, float inv_ne,
    const float* __restrict__ gamma, const float* __restrict__ beta,
    const float* __restrict__ wdir, float* __restrict__ u, float* __restrict__ bconst)
{
    int c = threadIdx.x & 511;
    int h = threadIdx.x >> 9;
    float s = 0.f, q = 0.f;
    for (int b = h * 128; b < h * 128 + 128; b += 8) {
        #pragma unroll
        for (int t = 0; t < 8; ++t) {
            s += part[(size_t)(b + t) * 1024 + c];
            q += part[(size_t)(b + t) * 1024 + 512 + c];
        }
    }
    __shared__ float sh_s[512], sh_q[512], red[512];
    if (h == 0) { sh_s[c] = s; sh_q[c] = q; }
    __syncthreads();
    if (h == 1) { sh_s[c] += s; sh_q[c] += q; }
    __syncthreads();
    if (h == 0) {
        float mean = sh_s[c] * inv_ne;
        float var  = sh_q[c] * inv_ne - mean * mean;
        float sc   = gamma[c] / sqrtf(var + 1e-5f);
        u[c] = sc * wdir[c];
        red[c] = (beta[c] - mean * sc) * wdir[c];
    }
    __syncthreads();
    for (int st = 256; st > 0; st >>= 1) {
        if (threadIdx.x < st) red[threadIdx.x] += red[threadIdx.x + st];
        __syncthreads();
    }
    if (threadIdx.x == 0) *bconst = red[0];
}

// ---------------- Kernel 3: weights fp32 -> bf16 ---------------------------
__global__ __launch_bounds__(256) void conv_w(
    const float* __restrict__ a, const float* __restrict__ b,
    unsigned short* __restrict__ oa, unsigned short* __restrict__ ob)
{
    int i = blockIdx.x * 256 + threadIdx.x;
    oa[i] = f2bf(a[i]);
    ob[i] = f2bf(b[i]);
}

// ---------------- Kernel 4: per-n gates + adjacency + agg ------------------
__global__ __launch_bounds__(512) void fuse_graph(
    const unsigned short* __restrict__ xbf, const float* __restrict__ adj,
    const int* __restrict__ ei, const int* __restrict__ ej,
    const float* __restrict__ u, const float* __restrict__ bconst,
    unsigned short* __restrict__ aggbf)
{
    __shared__ float Dl[13];
    __shared__ float Wl[K_NODES * K_NODES];
    __shared__ float rnorm[K_NODES];
    int n = blockIdx.x, c = threadIdx.x;
    size_t base = (size_t)n * K_NODES * C_DIM + c;

    float xv[K_NODES];
    #pragma unroll
    for (int k = 0; k < K_NODES; ++k) xv[k] = bf2f(xbf[base + k * C_DIM]);

    if (c < 13) Dl[c] = 0.f;
    __syncthreads();

    float g  = xv[13];
    float uc = u[c];
    #pragma unroll
    for (int k = 0; k < 13; ++k) {
        float val = fabsf(xv[k] - g) * uc;
        #pragma unroll
        for (int off = 32; off > 0; off >>= 1) val += __shfl_down(val, off, 64);
        if ((c & 63) == 0) atomicAdd(&Dl[k], val);
    }
    __syncthreads();

    if (c < K_NODES * K_NODES) Wl[c] = 1.f;
    __syncthreads();
    if (c < N_EDGE) {
        float z = 4.0f * (15.f * (Dl[ei[c]] - Dl[ej[c]]) + *bconst);
        float a = 1.f / (1.f + expf(-z));
        Wl[ei[c] * K_NODES + ej[c]] = 2.f * a;
        Wl[ej[c] * K_NODES + ei[c]] = 2.f * (1.f - a);
    }
    __syncthreads();
    if (c < K_NODES * K_NODES) Wl[c] *= adj[c];
    __syncthreads();
    if (c < K_NODES) {
        float s = 0.f;
        #pragma unroll
        for (int j = 0; j < K_NODES; ++j) s += fabsf(Wl[c * K_NODES + j]);
        rnorm[c] = fmaxf(s, 1e-12f);
    }
    __syncthreads();
    if (c < K_NODES * K_NODES) Wl[c] /= rnorm[c / K_NODES];
    __syncthreads();

    #pragma unroll
    for (int i = 0; i < K_NODES; ++i) {
        float s = 0.f;
        #pragma unroll
        for (int j = 0; j < K_NODES; ++j) s += Wl[i * K_NODES + j] * xv[j];
        aggbf[base + i * C_DIM] = f2bf(s);
    }
}

// ---------------- Kernel 5: fused GEMM: relu(agg@Wm^T) + x@Wo^T ------------
// m97 structure: 128x128 tile, BK=64, global_load_lds width=16, unpadded LDS
#define TM 128
#define TN 128
#define BK 64

__global__ __launch_bounds__(256) void gemm_fused(
    const unsigned short* __restrict__ Aagg, const unsigned short* __restrict__ Axin,
    const unsigned short* __restrict__ Bwm,  const unsigned short* __restrict__ Bwo,
    float* __restrict__ out)
{
    __shared__ unsigned short lA[TM * BK];   // 16 KB
    __shared__ unsigned short lB[TN * BK];   // 16 KB
    int tid  = threadIdx.x;
    int lane = tid & 63;
    int wave = tid >> 6;
    int wr = wave >> 1, wc = wave & 1;
    int bm = blockIdx.x * TM;
    int bn = blockIdx.y * TN;

    f32x4 acc[4][4];
    #pragma unroll
    for (int i = 0; i < 4; ++i)
        #pragma unroll
        for (int j = 0; j < 4; ++j) acc[i][j] = (f32x4){0.f, 0.f, 0.f, 0.f};

    int lrow = lane & 15;
    int lko  = (lane >> 4) * 8;     // 16B chunk within 32-wide k-step

    #pragma unroll
    for (int pass = 0; pass < 2; ++pass) {
        const unsigned short* A = pass ? Axin : Aagg;
        const unsigned short* B = pass ? Bwo  : Bwm;
        for (int kb = 0; kb < C_DIM; kb += BK) {
            __syncthreads();
            #pragma unroll
            for (int it = 0; it < 4; ++it) {
                int p   = it * 256 + tid;       // 0..1023 16B-chunks
                int row = p >> 3;               // 8 chunks (128B) per row
                int ch  = (p & 7) * 8;          // ushort offset within row
                // wave-uniform LDS dest; HW adds lane*16
                async16(A + (size_t)(bm + row) * C_DIM + kb + ch,
                        &lA[(size_t)(it * 256 + wave * 64) * 8]);
                async16(B + (size_t)(bn + row) * C_DIM + kb + ch,
                        &lB[(size_t)(it * 256 + wave * 64) * 8]);
            }
            __syncthreads();
            #pragma unroll
            for (int ks = 0; ks < 2; ++ks) {
                bf16x8 af[4], bfr[4];
                #pragma unroll
                for (int i = 0; i < 4; ++i)
                    af[i] = *(const bf16x8*)&lA[(wr * 64 + i * 16 + lrow) * BK + ks * 32 + lko];
                #pragma unroll
                for (int j = 0; j < 4; ++j)
                    bfr[j] = *(const bf16x8*)&lB[(wc * 64 + j * 16 + lrow) * BK + ks * 32 + lko];
                #pragma unroll
                for (int i = 0; i < 4; ++i)
                    #pragma unroll
                    for (int j = 0; j < 4; ++j)
                        acc[i][j] = __builtin_amdgcn_mfma_f32_16x16x32_bf16(
                            af[i], bfr[j], acc[i][j], 0, 0, 0);
            }
        }
        if (pass == 0) {
            #pragma unroll
            for (int i = 0; i < 4; ++i)
                #pragma unroll
                for (int j = 0; j < 4; ++j)
                    #pragma unroll
                    for (int r = 0; r < 4; ++r)
                        acc[i][j][r] = fmaxf(acc[i][j][r], 0.f);
        }
    }

    int orow0 = bm + wr * 64 + (lane >> 4) * 4;
    int ocol0 = bn + wc * 64 + (lane & 15);
    #pragma unroll
    for (int i = 0; i < 4; ++i)
        #pragma unroll
        for (int j = 0; j < 4; ++j)
            #pragma unroll
            for (int r = 0; r < 4; ++r)
                out[(size_t)(orow0 + i * 16 + r) * OUT_DIM + (ocol0 + j * 16)] = acc[i][j][r];
}

extern "C" void kernel_launch(void* const* d_in, const int* in_sizes, int n_in,
                              void* d_out, int out_size, void* d_ws, size_t ws_size,
                              hipStream_t stream)
{
    const float* x     = (const float*)d_in[0];
    const float* adj   = (const float*)d_in[1];
    const int*   ei    = (const int*)d_in[2];
    const int*   ej    = (const int*)d_in[3];
    const float* gamma = (const float*)d_in[4];
    const float* beta  = (const float*)d_in[5];
    const float* wdir  = (const float*)d_in[6];
    const float* Wm    = (const float*)d_in[7];
    const float* Wo    = (const float*)d_in[8];
    float* out = (float*)d_out;

    int N = in_sizes[0] / (K_NODES * C_DIM);   // 2048
    int M = N * K_NODES;                        // 28672

    float* ws_f   = (float*)d_ws;
    float* u      = ws_f + 1024;               // [512]
    float* bconst = ws_f + 1536;               // [1]
    float* part   = ws_f + 2048;               // [256*1024]
    char*  wsb    = (char*)d_ws;
    size_t off    = (size_t)(2048 + 256 * 1024) * sizeof(float);
    unsigned short* wmbf  = (unsigned short*)(wsb + off);  off += (size_t)OUT_DIM * C_DIM * 2;
    unsigned short* wobf  = (unsigned short*)(wsb + off);  off += (size_t)OUT_DIM * C_DIM * 2;
    unsigned short* xbf   = (unsigned short*)(wsb + off);  off += (size_t)M * C_DIM * 2;
    unsigned short* aggbf = (unsigned short*)(wsb + off);

    const int stats_blocks = 256;
    int n_per_block = N / stats_blocks;
    float inv_ne = 1.0f / ((float)N * (float)N_EDGE);

    hipLaunchKernelGGL(stats_partial, dim3(stats_blocks), dim3(512), 0, stream,
                       x, part, xbf, n_per_block);
    hipLaunchKernelGGL(finalize_stats, dim3(1), dim3(1024), 0, stream,
                       part, inv_ne, gamma, beta, wdir, u, bconst);
    hipLaunchKernelGGL(conv_w, dim3((OUT_DIM * C_DIM) / 256), dim3(256), 0, stream,
                       Wm, Wo, wmbf, wobf);
    hipLaunchKernelGGL(fuse_graph, dim3(N), dim3(512), 0, stream,
                       xbf, adj, ei, ej, u, bconst, aggbf);
    hipLaunchKernelGGL(gemm_fused, dim3(M / TM, OUT_DIM / TN), dim3(256), 0, stream,
                       aggbf, xbf, wmbf, wobf, out);
}

// Round 3
// 204.178 us; speedup vs baseline: 1.3114x; 1.0577x over previous
//
#include <hip/hip_runtime.h>
#include <stdint.h>

#define K_NODES 14
#define C_DIM   512
#define OUT_DIM 512
#define N_EDGE  78

typedef float  f32x4  __attribute__((ext_vector_type(4)));
typedef __bf16 bf16x8 __attribute__((ext_vector_type(8)));

__device__ __forceinline__ unsigned short f2bf(float f) {
    unsigned int u = __builtin_bit_cast(unsigned int, f);
    unsigned int r = (u + 0x7fffu + ((u >> 16) & 1u)) >> 16;  // RNE
    return (unsigned short)r;
}
__device__ __forceinline__ float bf2f(unsigned short s) {
    return __builtin_bit_cast(float, (unsigned int)s << 16);
}

// async 16B global -> LDS (LDS dest is wave-uniform base; HW adds lane*16)
__device__ __forceinline__ void async16(const void* g, void* l) {
    __builtin_amdgcn_global_load_lds(
        (const __attribute__((address_space(1))) unsigned int*)g,
        (__attribute__((address_space(3))) unsigned int*)l, 16, 0, 0);
}

// ------- Kernel 1: per-channel stats partials + x->bf16 + weights->bf16 ----
// d_k = |x[n,k,c]-x[n,13,c]|  (k=0..12)
// sum_e gap = 15*sum_k (12-2k) d_k ; sum_e gap^2 = 225*(13*sum d^2 - (sum d)^2)
__global__ __launch_bounds__(512) void stats_partial(
    const float* __restrict__ x, float* __restrict__ part,
    unsigned short* __restrict__ xbf, int n_per_block,
    const float* __restrict__ Wm, const float* __restrict__ Wo,
    unsigned short* __restrict__ wmbf, unsigned short* __restrict__ wobf,
    float* __restrict__ bconst)
{
    int c  = threadIdx.x;
    int n0 = blockIdx.x * n_per_block;
    float s_sum = 0.f, s_sq = 0.f;
    for (int nn = 0; nn < n_per_block; ++nn) {
        size_t base = (size_t)(n0 + nn) * K_NODES * C_DIM + c;
        const float* xb = x + base;
        unsigned short* xo = xbf + base;
        float g = xb[13 * C_DIM];
        xo[13 * C_DIM] = f2bf(g);
        float S1 = 0.f, S2 = 0.f, Sw = 0.f;
        #pragma unroll
        for (int k = 0; k < 13; ++k) {
            float v = xb[k * C_DIM];
            xo[k * C_DIM] = f2bf(v);
            float d = fabsf(v - g);
            S1 += d; S2 += d * d; Sw += (float)(12 - 2 * k) * d;
        }
        s_sum += 15.f * Sw;
        s_sq  += 225.f * (13.f * S2 - S1 * S1);
    }
    part[(size_t)blockIdx.x * 1024 + c]       = s_sum;
    part[(size_t)blockIdx.x * 1024 + 512 + c] = s_sq;
    // fold in weight conversion (1024 elems of each matrix per block)
    {
        int i0 = blockIdx.x * 1024 + c;
        wmbf[i0]       = f2bf(Wm[i0]);
        wmbf[i0 + 512] = f2bf(Wm[i0 + 512]);
        wobf[i0]       = f2bf(Wo[i0]);
        wobf[i0 + 512] = f2bf(Wo[i0 + 512]);
    }
    if (blockIdx.x == 0 && c == 0) *bconst = 0.f;  // harmless pre-zero (unused path)
}

// ---------------- Kernel 2: finalize stats -> u[c], Bconst -----------------
__global__ __launch_bounds__(1024) void finalize_stats(
    const float* __restrict__ part, float inv_ne,
    const float* __restrict__ gamma, const float* __restrict__ beta,
    const float* __restrict__ wdir, float* __restrict__ u, float* __restrict__ bconst)
{
    int c = threadIdx.x & 511;
    int h = threadIdx.x >> 9;
    float s = 0.f, q = 0.f;
    for (int b = h * 128; b < h * 128 + 128; b += 8) {
        #pragma unroll
        for (int t = 0; t < 8; ++t) {
            s += part[(size_t)(b + t) * 1024 + c];
            q += part[(size_t)(b + t) * 1024 + 512 + c];
        }
    }
    __shared__ float sh_s[512], sh_q[512], red[512];
    if (h == 0) { sh_s[c] = s; sh_q[c] = q; }
    __syncthreads();
    if (h == 1) { sh_s[c] += s; sh_q[c] += q; }
    __syncthreads();
    if (h == 0) {
        float mean = sh_s[c] * inv_ne;
        float var  = sh_q[c] * inv_ne - mean * mean;
        float sc   = gamma[c] / sqrtf(var + 1e-5f);
        u[c] = sc * wdir[c];
        red[c] = (beta[c] - mean * sc) * wdir[c];
    }
    __syncthreads();
    for (int st = 256; st > 0; st >>= 1) {
        if (threadIdx.x < st) red[threadIdx.x] += red[threadIdx.x + st];
        __syncthreads();
    }
    if (threadIdx.x == 0) *bconst = red[0];
}

// ---------------- Kernel 3: per-n gates + adjacency + agg ------------------
__global__ __launch_bounds__(512) void fuse_graph(
    const unsigned short* __restrict__ xbf, const float* __restrict__ adj,
    const int* __restrict__ ei, const int* __restrict__ ej,
    const float* __restrict__ u, const float* __restrict__ bconst,
    unsigned short* __restrict__ aggbf)
{
    __shared__ float Dl[13];
    __shared__ float Wl[K_NODES * K_NODES];
    __shared__ float rnorm[K_NODES];
    int n = blockIdx.x, c = threadIdx.x;
    size_t base = (size_t)n * K_NODES * C_DIM + c;

    float xv[K_NODES];
    #pragma unroll
    for (int k = 0; k < K_NODES; ++k) xv[k] = bf2f(xbf[base + k * C_DIM]);

    if (c < 13) Dl[c] = 0.f;
    __syncthreads();

    float g  = xv[13];
    float uc = u[c];
    #pragma unroll
    for (int k = 0; k < 13; ++k) {
        float val = fabsf(xv[k] - g) * uc;
        #pragma unroll
        for (int off = 32; off > 0; off >>= 1) val += __shfl_down(val, off, 64);
        if ((c & 63) == 0) atomicAdd(&Dl[k], val);
    }
    __syncthreads();

    if (c < K_NODES * K_NODES) Wl[c] = 1.f;
    __syncthreads();
    if (c < N_EDGE) {
        float z = 4.0f * (15.f * (Dl[ei[c]] - Dl[ej[c]]) + *bconst);
        float a = 1.f / (1.f + expf(-z));
        Wl[ei[c] * K_NODES + ej[c]] = 2.f * a;
        Wl[ej[c] * K_NODES + ei[c]] = 2.f * (1.f - a);
    }
    __syncthreads();
    if (c < K_NODES * K_NODES) Wl[c] *= adj[c];
    __syncthreads();
    if (c < K_NODES) {
        float s = 0.f;
        #pragma unroll
        for (int j = 0; j < K_NODES; ++j) s += fabsf(Wl[c * K_NODES + j]);
        rnorm[c] = fmaxf(s, 1e-12f);
    }
    __syncthreads();
    if (c < K_NODES * K_NODES) Wl[c] /= rnorm[c / K_NODES];
    __syncthreads();

    #pragma unroll
    for (int i = 0; i < K_NODES; ++i) {
        float s = 0.f;
        #pragma unroll
        for (int j = 0; j < K_NODES; ++j) s += Wl[i * K_NODES + j] * xv[j];
        aggbf[base + i * C_DIM] = f2bf(s);
    }
}

// ---------------- Kernel 4: fused GEMM: relu(agg@Wm^T) + x@Wo^T ------------
// 128x128 tile, BK=64, global_load_lds width=16, XOR-swizzled LDS:
// LDS chunk (row, pc) holds logical 16B chunk lc = pc ^ (row&7).
#define TM 128
#define TN 128
#define BK 64

__global__ __launch_bounds__(256) void gemm_fused(
    const unsigned short* __restrict__ Aagg, const unsigned short* __restrict__ Axin,
    const unsigned short* __restrict__ Bwm,  const unsigned short* __restrict__ Bwo,
    float* __restrict__ out)
{
    __shared__ unsigned short lA[TM * BK];   // 16 KB
    __shared__ unsigned short lB[TN * BK];   // 16 KB
    int tid  = threadIdx.x;
    int lane = tid & 63;
    int wave = tid >> 6;
    int wr = wave >> 1, wc = wave & 1;
    int bm = blockIdx.x * TM;
    int bn = blockIdx.y * TN;

    f32x4 acc[4][4];
    #pragma unroll
    for (int i = 0; i < 4; ++i)
        #pragma unroll
        for (int j = 0; j < 4; ++j) acc[i][j] = (f32x4){0.f, 0.f, 0.f, 0.f};

    int lrow = lane & 15;
    int xorv = lane & 7;                 // row&7 of every fragment row this lane reads
    // staging: thread tid stages LDS chunk p = it*256+tid; row = it*32+(tid>>3)
    int srow  = tid >> 3;                // 0..31 (row within 32-row slab)
    int lcu   = ((tid & 7) ^ (srow & 7)) * 8;  // swizzled logical chunk, ushort offset

    #pragma unroll
    for (int pass = 0; pass < 2; ++pass) {
        const unsigned short* A = pass ? Axin : Aagg;
        const unsigned short* B = pass ? Bwo  : Bwm;
        for (int kb = 0; kb < C_DIM; kb += BK) {
            __syncthreads();
            #pragma unroll
            for (int it = 0; it < 4; ++it) {
                int row = it * 32 + srow;
                async16(A + (size_t)(bm + row) * C_DIM + kb + lcu,
                        &lA[(size_t)(it * 256 + wave * 64) * 8]);
                async16(B + (size_t)(bn + row) * C_DIM + kb + lcu,
                        &lB[(size_t)(it * 256 + wave * 64) * 8]);
            }
            __syncthreads();
            #pragma unroll
            for (int ks = 0; ks < 2; ++ks) {
                int pchunk = ((ks * 4 + (lane >> 4)) ^ xorv) * 8;  // physical chunk, ushorts
                bf16x8 af[4], bfr[4];
                #pragma unroll
                for (int i = 0; i < 4; ++i)
                    af[i] = *(const bf16x8*)&lA[(wr * 64 + i * 16 + lrow) * BK + pchunk];
                #pragma unroll
                for (int j = 0; j < 4; ++j)
                    bfr[j] = *(const bf16x8*)&lB[(wc * 64 + j * 16 + lrow) * BK + pchunk];
                #pragma unroll
                for (int i = 0; i < 4; ++i)
                    #pragma unroll
                    for (int j = 0; j < 4; ++j)
                        acc[i][j] = __builtin_amdgcn_mfma_f32_16x16x32_bf16(
                            af[i], bfr[j], acc[i][j], 0, 0, 0);
            }
        }
        if (pass == 0) {
            #pragma unroll
            for (int i = 0; i < 4; ++i)
                #pragma unroll
                for (int j = 0; j < 4; ++j)
                    #pragma unroll
                    for (int r = 0; r < 4; ++r)
                        acc[i][j][r] = fmaxf(acc[i][j][r], 0.f);
        }
    }

    int orow0 = bm + wr * 64 + (lane >> 4) * 4;
    int ocol0 = bn + wc * 64 + (lane & 15);
    #pragma unroll
    for (int i = 0; i < 4; ++i)
        #pragma unroll
        for (int j = 0; j < 4; ++j)
            #pragma unroll
            for (int r = 0; r < 4; ++r)
                out[(size_t)(orow0 + i * 16 + r) * OUT_DIM + (ocol0 + j * 16)] = acc[i][j][r];
}

extern "C" void kernel_launch(void* const* d_in, const int* in_sizes, int n_in,
                              void* d_out, int out_size, void* d_ws, size_t ws_size,
                              hipStream_t stream)
{
    const float* x     = (const float*)d_in[0];
    const float* adj   = (const float*)d_in[1];
    const int*   ei    = (const int*)d_in[2];
    const int*   ej    = (const int*)d_in[3];
    const float* gamma = (const float*)d_in[4];
    const float* beta  = (const float*)d_in[5];
    const float* wdir  = (const float*)d_in[6];
    const float* Wm    = (const float*)d_in[7];
    const float* Wo    = (const float*)d_in[8];
    float* out = (float*)d_out;

    int N = in_sizes[0] / (K_NODES * C_DIM);   // 2048
    int M = N * K_NODES;                        // 28672

    float* ws_f   = (float*)d_ws;
    float* u      = ws_f + 1024;               // [512]
    float* bconst = ws_f + 1536;               // [1]
    float* part   = ws_f + 2048;               // [256*1024]
    char*  wsb    = (char*)d_ws;
    size_t off    = (size_t)(2048 + 256 * 1024) * sizeof(float);
    unsigned short* wmbf  = (unsigned short*)(wsb + off);  off += (size_t)OUT_DIM * C_DIM * 2;
    unsigned short* wobf  = (unsigned short*)(wsb + off);  off += (size_t)OUT_DIM * C_DIM * 2;
    unsigned short* xbf   = (unsigned short*)(wsb + off);  off += (size_t)M * C_DIM * 2;
    unsigned short* aggbf = (unsigned short*)(wsb + off);

    const int stats_blocks = 256;
    int n_per_block = N / stats_blocks;
    float inv_ne = 1.0f / ((float)N * (float)N_EDGE);

    hipLaunchKernelGGL(stats_partial, dim3(stats_blocks), dim3(512), 0, stream,
                       x, part, xbf, n_per_block, Wm, Wo, wmbf, wobf, bconst);
    hipLaunchKernelGGL(finalize_stats, dim3(1), dim3(1024), 0, stream,
                       part, inv_ne, gamma, beta, wdir, u, bconst);
    hipLaunchKernelGGL(fuse_graph, dim3(N), dim3(512), 0, stream,
                       xbf, adj, ei, ej, u, bconst, aggbf);
    hipLaunchKernelGGL(gemm_fused, dim3(M / TM, OUT_DIM / TN), dim3(256), 0, stream,
                       aggbf, xbf, wmbf, wobf, out);
}

// Round 5
// 193.497 us; speedup vs baseline: 1.3838x; 1.0552x over previous
//
#include <hip/hip_runtime.h>
#include <stdint.h>

#define K_NODES 14
#define C_DIM   512
#define OUT_DIM 512
#define N_EDGE  78

typedef float  f32x4  __attribute__((ext_vector_type(4)));
typedef __bf16 bf16x8 __attribute__((ext_vector_type(8)));

__device__ __forceinline__ unsigned short f2bf(float f) {
    unsigned int u = __builtin_bit_cast(unsigned int, f);
    unsigned int r = (u + 0x7fffu + ((u >> 16) & 1u)) >> 16;  // RNE
    return (unsigned short)r;
}
__device__ __forceinline__ float bf2f(unsigned short s) {
    return __builtin_bit_cast(float, (unsigned int)s << 16);
}

// async 16B global -> LDS (LDS dest is wave-uniform base; HW adds lane*16)
__device__ __forceinline__ void async16(const void* g, void* l) {
    __builtin_amdgcn_global_load_lds(
        (const __attribute__((address_space(1))) unsigned int*)g,
        (__attribute__((address_space(3))) unsigned int*)l, 16, 0, 0);
}

// ------- Kernel 1: per-channel stats partials + x->bf16 + weights->bf16 ----
// d_k = |x[n,k,c]-x[n,13,c]| (k=0..12)
// sum_e gap = 15*sum_k (12-2k) d_k ; sum_e gap^2 = 225*(13*sum d^2 - (sum d)^2)
// 512 thr: q = tid&127 -> channel quad c=4q..4q+3 ; sn = tid>>7 -> sample slot
__global__ __launch_bounds__(512) void stats_partial(
    const float* __restrict__ x, float* __restrict__ part,
    unsigned short* __restrict__ xbf, int n_per_block,
    const float* __restrict__ Wm, const float* __restrict__ Wo,
    unsigned short* __restrict__ wmbf, unsigned short* __restrict__ wobf)
{
    int t  = threadIdx.x;
    int q  = t & 127;
    int sn = t >> 7;
    int n0 = blockIdx.x * n_per_block;
    float as0=0.f,as1=0.f,as2=0.f,as3=0.f;
    float aq0=0.f,aq1=0.f,aq2=0.f,aq3=0.f;
    for (int nn = sn; nn < n_per_block; nn += 4) {
        size_t base = (size_t)(n0 + nn) * K_NODES * C_DIM + q * 4;
        f32x4 g = *(const f32x4*)(x + base + 13 * C_DIM);
        ushort4 gb; gb.x=f2bf(g.x); gb.y=f2bf(g.y); gb.z=f2bf(g.z); gb.w=f2bf(g.w);
        *(ushort4*)(xbf + base + 13 * C_DIM) = gb;
        float S10=0,S11=0,S12=0,S13=0, S20=0,S21=0,S22=0,S23=0, Sw0=0,Sw1=0,Sw2=0,Sw3=0;
        #pragma unroll
        for (int k = 0; k < 13; ++k) {
            f32x4 v = *(const f32x4*)(x + base + k * C_DIM);
            ushort4 vb; vb.x=f2bf(v.x); vb.y=f2bf(v.y); vb.z=f2bf(v.z); vb.w=f2bf(v.w);
            *(ushort4*)(xbf + base + k * C_DIM) = vb;
            float wk = (float)(12 - 2 * k);
            float d0=fabsf(v.x-g.x), d1=fabsf(v.y-g.y), d2=fabsf(v.z-g.z), d3=fabsf(v.w-g.w);
            S10+=d0; S11+=d1; S12+=d2; S13+=d3;
            S20+=d0*d0; S21+=d1*d1; S22+=d2*d2; S23+=d3*d3;
            Sw0+=wk*d0; Sw1+=wk*d1; Sw2+=wk*d2; Sw3+=wk*d3;
        }
        as0 += 15.f*Sw0; as1 += 15.f*Sw1; as2 += 15.f*Sw2; as3 += 15.f*Sw3;
        aq0 += 225.f*(13.f*S20 - S10*S10); aq1 += 225.f*(13.f*S21 - S11*S11);
        aq2 += 225.f*(13.f*S22 - S12*S12); aq3 += 225.f*(13.f*S23 - S13*S13);
    }
    __shared__ f32x4 redS[4][128];
    __shared__ f32x4 redQ[4][128];
    redS[sn][q] = (f32x4){as0, as1, as2, as3};
    redQ[sn][q] = (f32x4){aq0, aq1, aq2, aq3};
    __syncthreads();
    if (sn == 0) {
        f32x4 s = redS[0][q] + redS[1][q] + redS[2][q] + redS[3][q];
        f32x4 z = redQ[0][q] + redQ[1][q] + redQ[2][q] + redQ[3][q];
        *(f32x4*)(part + (size_t)blockIdx.x * 1024 + q * 4)       = s;
        *(f32x4*)(part + (size_t)blockIdx.x * 1024 + 512 + q * 4) = z;
    }
    // fold in weight conversion (1024 elems of each matrix per block)
    int i0 = blockIdx.x * 1024 + t;
    wmbf[i0]       = f2bf(Wm[i0]);
    wmbf[i0 + 512] = f2bf(Wm[i0 + 512]);
    wobf[i0]       = f2bf(Wo[i0]);
    wobf[i0 + 512] = f2bf(Wo[i0 + 512]);
}

// ---------------- Kernel 2: finalize stats -> u[c], Bconst -----------------
__global__ __launch_bounds__(1024) void finalize_stats(
    const float* __restrict__ part, float inv_ne,
    const float* __restrict__ gamma, const float* __restrict__ beta,
    const float* __restrict__ wdir, float* __restrict__ u, float* __restrict__ bconst)
{
    int c = threadIdx.x & 511;
    int h = threadIdx.x >> 9;
    float s = 0.f, q = 0.f;
    for (int b = h * 128; b < h * 128 + 128; b += 16) {
        #pragma unroll
        for (int t = 0; t < 16; ++t) {
            s += part[(size_t)(b + t) * 1024 + c];
            q += part[(size_t)(b + t) * 1024 + 512 + c];
        }
    }
    __shared__ float sh_s[512], sh_q[512], red[512];
    if (h == 0) { sh_s[c] = s; sh_q[c] = q; }
    __syncthreads();
    if (h == 1) { sh_s[c] += s; sh_q[c] += q; }
    __syncthreads();
    if (h == 0) {
        float mean = sh_s[c] * inv_ne;
        float var  = sh_q[c] * inv_ne - mean * mean;
        float sc   = gamma[c] / sqrtf(var + 1e-5f);
        u[c] = sc * wdir[c];
        red[c] = (beta[c] - mean * sc) * wdir[c];
    }
    __syncthreads();
    for (int st = 256; st > 0; st >>= 1) {
        if (threadIdx.x < st) red[threadIdx.x] += red[threadIdx.x + st];
        __syncthreads();
    }
    if (threadIdx.x == 0) *bconst = red[0];
}

// ---------------- Kernel 3: per-n gates + adjacency + agg ------------------
// one wave per sample: lane owns 8 channels; 4 samples per 256-thr block
__global__ __launch_bounds__(256) void fuse_graph(
    const unsigned short* __restrict__ xbf, const float* __restrict__ adj,
    const int* __restrict__ ei, const int* __restrict__ ej,
    const float* __restrict__ u, const float* __restrict__ bconst,
    unsigned short* __restrict__ aggbf)
{
    __shared__ float WL[4][196];
    __shared__ float DlL[4][16];
    __shared__ float invL[4][16];
    int wv = threadIdx.x >> 6, lane = threadIdx.x & 63;
    int n = blockIdx.x * 4 + wv;
    size_t base = (size_t)n * K_NODES * C_DIM + lane * 8;

    // load 14 x-rows (8 bf16 each) and convert to fp32
    float xf[K_NODES][8];
    #pragma unroll
    for (int k = 0; k < K_NODES; ++k) {
        uint4 raw = *(const uint4*)(xbf + base + k * C_DIM);
        unsigned int w0=raw.x, w1=raw.y, w2=raw.z, w3=raw.w;
        xf[k][0]=bf2f(w0&0xffff); xf[k][1]=bf2f(w0>>16);
        xf[k][2]=bf2f(w1&0xffff); xf[k][3]=bf2f(w1>>16);
        xf[k][4]=bf2f(w2&0xffff); xf[k][5]=bf2f(w2>>16);
        xf[k][6]=bf2f(w3&0xffff); xf[k][7]=bf2f(w3>>16);
    }
    f32x4 u0 = *(const f32x4*)(u + lane * 8);
    f32x4 u1 = *(const f32x4*)(u + lane * 8 + 4);
    float uc[8] = {u0.x,u0.y,u0.z,u0.w,u1.x,u1.y,u1.z,u1.w};

    // D_k = sum_c |x_k - x_13| * u_c  (wave butterfly reduce)
    #pragma unroll
    for (int k = 0; k < 13; ++k) {
        float p = 0.f;
        #pragma unroll
        for (int j = 0; j < 8; ++j) p += fabsf(xf[k][j] - xf[13][j]) * uc[j];
        #pragma unroll
        for (int off = 1; off < 64; off <<= 1) p += __shfl_xor(p, off, 64);
        if (lane == 0) DlL[wv][k] = p;
    }
    __syncthreads();

    // gated adjacency (init with adj, multiply gates on edges)
    #pragma unroll
    for (int e = 0; e < 4; ++e) {
        int idx = e * 64 + lane;
        if (idx < 196) WL[wv][idx] = adj[idx];
    }
    __syncthreads();
    // N_EDGE=78 > 64 lanes: each lane handles edges lane and lane+64
    for (int e = lane; e < N_EDGE; e += 64) {
        int ii = ei[e], jj = ej[e];
        float z = 4.0f * (15.f * (DlL[wv][ii] - DlL[wv][jj]) + *bconst);
        float a = 1.f / (1.f + expf(-z));
        WL[wv][ii * K_NODES + jj] *= 2.f * a;
        WL[wv][jj * K_NODES + ii] *= 2.f * (1.f - a);
    }
    __syncthreads();
    if (lane < K_NODES) {
        float s = 0.f;
        #pragma unroll
        for (int j = 0; j < K_NODES; ++j) s += fabsf(WL[wv][lane * K_NODES + j]);
        invL[wv][lane] = 1.f / fmaxf(s, 1e-12f);
    }
    __syncthreads();

    // agg[i][c] = inv[i] * sum_j W[i][j] * x[j][c]
    #pragma unroll
    for (int i = 0; i < K_NODES; ++i) {
        float s[8] = {0,0,0,0,0,0,0,0};
        #pragma unroll
        for (int j = 0; j < K_NODES; ++j) {
            float w = WL[wv][i * K_NODES + j];
            #pragma unroll
            for (int c = 0; c < 8; ++c) s[c] += w * xf[j][c];
        }
        float wi = invL[wv][i];
        uint4 r;
        r.x = (unsigned int)f2bf(s[0]*wi) | ((unsigned int)f2bf(s[1]*wi) << 16);
        r.y = (unsigned int)f2bf(s[2]*wi) | ((unsigned int)f2bf(s[3]*wi) << 16);
        r.z = (unsigned int)f2bf(s[4]*wi) | ((unsigned int)f2bf(s[5]*wi) << 16);
        r.w = (unsigned int)f2bf(s[6]*wi) | ((unsigned int)f2bf(s[7]*wi) << 16);
        *(uint4*)(aggbf + base + i * C_DIM) = r;
    }
}

// ---------------- Kernel 4: fused GEMM: relu(agg@Wm^T) + x@Wo^T ------------
// 128x128 tile, BK=64, global_load_lds width=16, XOR-swizzled LDS:
// LDS chunk (row, pc) holds logical 16B chunk lc = pc ^ (row&7).
#define TM 128
#define TN 128
#define BK 64

__global__ __launch_bounds__(256) void gemm_fused(
    const unsigned short* __restrict__ Aagg, const unsigned short* __restrict__ Axin,
    const unsigned short* __restrict__ Bwm,  const unsigned short* __restrict__ Bwo,
    float* __restrict__ out)
{
    __shared__ unsigned short lA[TM * BK];   // 16 KB
    __shared__ unsigned short lB[TN * BK];   // 16 KB
    int tid  = threadIdx.x;
    int lane = tid & 63;
    int wave = tid >> 6;
    int wr = wave >> 1, wc = wave & 1;
    int bm = blockIdx.x * TM;
    int bn = blockIdx.y * TN;

    f32x4 acc[4][4];
    #pragma unroll
    for (int i = 0; i < 4; ++i)
        #pragma unroll
        for (int j = 0; j < 4; ++j) acc[i][j] = (f32x4){0.f, 0.f, 0.f, 0.f};

    int lrow = lane & 15;
    int xorv = lane & 7;
    int srow  = tid >> 3;
    int lcu   = ((tid & 7) ^ (srow & 7)) * 8;

    #pragma unroll
    for (int pass = 0; pass < 2; ++pass) {
        const unsigned short* A = pass ? Axin : Aagg;
        const unsigned short* B = pass ? Bwo  : Bwm;
        for (int kb = 0; kb < C_DIM; kb += BK) {
            __syncthreads();
            #pragma unroll
            for (int it = 0; it < 4; ++it) {
                int row = it * 32 + srow;
                async16(A + (size_t)(bm + row) * C_DIM + kb + lcu,
                        &lA[(size_t)(it * 256 + wave * 64) * 8]);
                async16(B + (size_t)(bn + row) * C_DIM + kb + lcu,
                        &lB[(size_t)(it * 256 + wave * 64) * 8]);
            }
            __syncthreads();
            #pragma unroll
            for (int ks = 0; ks < 2; ++ks) {
                int pchunk = ((ks * 4 + (lane >> 4)) ^ xorv) * 8;
                bf16x8 af[4], bfr[4];
                #pragma unroll
                for (int i = 0; i < 4; ++i)
                    af[i] = *(const bf16x8*)&lA[(wr * 64 + i * 16 + lrow) * BK + pchunk];
                #pragma unroll
                for (int j = 0; j < 4; ++j)
                    bfr[j] = *(const bf16x8*)&lB[(wc * 64 + j * 16 + lrow) * BK + pchunk];
                #pragma unroll
                for (int i = 0; i < 4; ++i)
                    #pragma unroll
                    for (int j = 0; j < 4; ++j)
                        acc[i][j] = __builtin_amdgcn_mfma_f32_16x16x32_bf16(
                            af[i], bfr[j], acc[i][j], 0, 0, 0);
            }
        }
        if (pass == 0) {
            #pragma unroll
            for (int i = 0; i < 4; ++i)
                #pragma unroll
                for (int j = 0; j < 4; ++j)
                    #pragma unroll
                    for (int r = 0; r < 4; ++r)
                        acc[i][j][r] = fmaxf(acc[i][j][r], 0.f);
        }
    }

    int orow0 = bm + wr * 64 + (lane >> 4) * 4;
    int ocol0 = bn + wc * 64 + (lane & 15);
    #pragma unroll
    for (int i = 0; i < 4; ++i)
        #pragma unroll
        for (int j = 0; j < 4; ++j)
            #pragma unroll
            for (int r = 0; r < 4; ++r)
                out[(size_t)(orow0 + i * 16 + r) * OUT_DIM + (ocol0 + j * 16)] = acc[i][j][r];
}

extern "C" void kernel_launch(void* const* d_in, const int* in_sizes, int n_in,
                              void* d_out, int out_size, void* d_ws, size_t ws_size,
                              hipStream_t stream)
{
    const float* x     = (const float*)d_in[0];
    const float* adj   = (const float*)d_in[1];
    const int*   ei    = (const int*)d_in[2];
    const int*   ej    = (const int*)d_in[3];
    const float* gamma = (const float*)d_in[4];
    const float* beta  = (const float*)d_in[5];
    const float* wdir  = (const float*)d_in[6];
    const float* Wm    = (const float*)d_in[7];
    const float* Wo    = (const float*)d_in[8];
    float* out = (float*)d_out;

    int N = in_sizes[0] / (K_NODES * C_DIM);   // 2048
    int M = N * K_NODES;                        // 28672

    float* ws_f   = (float*)d_ws;
    float* u      = ws_f + 1024;               // [512]
    float* bconst = ws_f + 1536;               // [1]
    float* part   = ws_f + 2048;               // [256*1024]
    char*  wsb    = (char*)d_ws;
    size_t off    = (size_t)(2048 + 256 * 1024) * sizeof(float);
    unsigned short* wmbf  = (unsigned short*)(wsb + off);  off += (size_t)OUT_DIM * C_DIM * 2;
    unsigned short* wobf  = (unsigned short*)(wsb + off);  off += (size_t)OUT_DIM * C_DIM * 2;
    unsigned short* xbf   = (unsigned short*)(wsb + off);  off += (size_t)M * C_DIM * 2;
    unsigned short* aggbf = (unsigned short*)(wsb + off);

    const int stats_blocks = 256;
    int n_per_block = N / stats_blocks;        // 8
    float inv_ne = 1.0f / ((float)N * (float)N_EDGE);

    hipLaunchKernelGGL(stats_partial, dim3(stats_blocks), dim3(512), 0, stream,
                       x, part, xbf, n_per_block, Wm, Wo, wmbf, wobf);
    hipLaunchKernelGGL(finalize_stats, dim3(1), dim3(1024), 0, stream,
                       part, inv_ne, gamma, beta, wdir, u, bconst);
    hipLaunchKernelGGL(fuse_graph, dim3(N / 4), dim3(256), 0, stream,
                       xbf, adj, ei, ej, u, bconst, aggbf);
    hipLaunchKernelGGL(gemm_fused, dim3(M / TM, OUT_DIM / TN), dim3(256), 0, stream,
                       aggbf, xbf, wmbf, wobf, out);
}

// Round 6
// 191.386 us; speedup vs baseline: 1.3990x; 1.0110x over previous
//
#include <hip/hip_runtime.h>
#include <stdint.h>

#define K_NODES 14
#define C_DIM   512
#define OUT_DIM 512
#define N_EDGE  78

typedef float  f32x4  __attribute__((ext_vector_type(4)));
typedef __bf16 bf16x8 __attribute__((ext_vector_type(8)));

__device__ __forceinline__ unsigned short f2bf(float f) {
    unsigned int u = __builtin_bit_cast(unsigned int, f);
    unsigned int r = (u + 0x7fffu + ((u >> 16) & 1u)) >> 16;  // RNE
    return (unsigned short)r;
}
__device__ __forceinline__ float bf2f(unsigned short s) {
    return __builtin_bit_cast(float, (unsigned int)s << 16);
}

// async 16B global -> LDS (LDS dest is wave-uniform base; HW adds lane*16)
__device__ __forceinline__ void async16(const void* g, void* l) {
    __builtin_amdgcn_global_load_lds(
        (const __attribute__((address_space(1))) unsigned int*)g,
        (__attribute__((address_space(3))) unsigned int*)l, 16, 0, 0);
}

// ------- Kernel 1: per-channel stats partials + x->bf16 + weights->bf16 ----
// One (sample, channel-quad) per thread: 1024 thr = 8 samples x 128 quads.
// d_k = |x[n,k,c]-x[n,13,c]| (k=0..12)
// sum_e gap = 15*sum_k (12-2k) d_k ; sum_e gap^2 = 225*(13*sum d^2 - (sum d)^2)
__global__ __launch_bounds__(1024) void stats_partial(
    const float* __restrict__ x, float* __restrict__ part,
    unsigned short* __restrict__ xbf,
    const float* __restrict__ Wm, const float* __restrict__ Wo,
    unsigned short* __restrict__ wmbf, unsigned short* __restrict__ wobf)
{
    int t  = threadIdx.x;
    int q  = t & 127;           // channel quad: channels 4q..4q+3
    int sn = t >> 7;            // sample slot 0..7
    int n  = blockIdx.x * 8 + sn;
    size_t base = (size_t)n * K_NODES * C_DIM + q * 4;

    f32x4 g = *(const f32x4*)(x + base + 13 * C_DIM);
    ushort4 gb; gb.x=f2bf(g.x); gb.y=f2bf(g.y); gb.z=f2bf(g.z); gb.w=f2bf(g.w);
    *(ushort4*)(xbf + base + 13 * C_DIM) = gb;

    float S10=0,S11=0,S12=0,S13=0, S20=0,S21=0,S22=0,S23=0, Sw0=0,Sw1=0,Sw2=0,Sw3=0;
    #pragma unroll
    for (int k = 0; k < 13; ++k) {
        f32x4 v = *(const f32x4*)(x + base + k * C_DIM);
        ushort4 vb; vb.x=f2bf(v.x); vb.y=f2bf(v.y); vb.z=f2bf(v.z); vb.w=f2bf(v.w);
        *(ushort4*)(xbf + base + k * C_DIM) = vb;
        float wk = (float)(12 - 2 * k);
        float d0=fabsf(v.x-g.x), d1=fabsf(v.y-g.y), d2=fabsf(v.z-g.z), d3=fabsf(v.w-g.w);
        S10+=d0; S11+=d1; S12+=d2; S13+=d3;
        S20+=d0*d0; S21+=d1*d1; S22+=d2*d2; S23+=d3*d3;
        Sw0+=wk*d0; Sw1+=wk*d1; Sw2+=wk*d2; Sw3+=wk*d3;
    }
    f32x4 as = (f32x4){15.f*Sw0, 15.f*Sw1, 15.f*Sw2, 15.f*Sw3};
    f32x4 aq = (f32x4){225.f*(13.f*S20 - S10*S10), 225.f*(13.f*S21 - S11*S11),
                       225.f*(13.f*S22 - S12*S12), 225.f*(13.f*S23 - S13*S13)};

    __shared__ f32x4 redS[8][128];
    __shared__ f32x4 redQ[8][128];
    redS[sn][q] = as;
    redQ[sn][q] = aq;
    __syncthreads();
    if (sn == 0) {
        f32x4 s = redS[0][q], z = redQ[0][q];
        #pragma unroll
        for (int r = 1; r < 8; ++r) { s += redS[r][q]; z += redQ[r][q]; }
        *(f32x4*)(part + (size_t)blockIdx.x * 1024 + q * 4)       = s;
        *(f32x4*)(part + (size_t)blockIdx.x * 1024 + 512 + q * 4) = z;
    }
    // fold in weight conversion (1024 elems of each matrix per block)
    int i0 = blockIdx.x * 1024 + t;
    wmbf[i0] = f2bf(Wm[i0]);
    wobf[i0] = f2bf(Wo[i0]);
}

// ---------------- Kernel 2: finalize stats -> u[c], Bconst -----------------
__global__ __launch_bounds__(1024) void finalize_stats(
    const float* __restrict__ part, float inv_ne,
    const float* __restrict__ gamma, const float* __restrict__ beta,
    const float* __restrict__ wdir, float* __restrict__ u, float* __restrict__ bconst)
{
    int c = threadIdx.x & 511;
    int h = threadIdx.x >> 9;
    float s = 0.f, q = 0.f;
    for (int b = h * 128; b < h * 128 + 128; b += 16) {
        #pragma unroll
        for (int t = 0; t < 16; ++t) {
            s += part[(size_t)(b + t) * 1024 + c];
            q += part[(size_t)(b + t) * 1024 + 512 + c];
        }
    }
    __shared__ float sh_s[512], sh_q[512], red[512];
    if (h == 0) { sh_s[c] = s; sh_q[c] = q; }
    __syncthreads();
    if (h == 1) { sh_s[c] += s; sh_q[c] += q; }
    __syncthreads();
    if (h == 0) {
        float mean = sh_s[c] * inv_ne;
        float var  = sh_q[c] * inv_ne - mean * mean;
        float sc   = gamma[c] / sqrtf(var + 1e-5f);
        u[c] = sc * wdir[c];
        red[c] = (beta[c] - mean * sc) * wdir[c];
    }
    __syncthreads();
    for (int st = 256; st > 0; st >>= 1) {
        if (threadIdx.x < st) red[threadIdx.x] += red[threadIdx.x + st];
        __syncthreads();
    }
    if (threadIdx.x == 0) *bconst = red[0];
}

// ---------------- Kernel 3: per-n gates + adjacency + agg ------------------
// TWO waves per sample (lane owns 4 channels): 256 thr = 2 samples.
// xf cache = 56 VGPRs (vs 112 in the 1-wave version) -> no spill risk.
__global__ __launch_bounds__(256) void fuse_graph(
    const unsigned short* __restrict__ xbf, const float* __restrict__ adj,
    const int* __restrict__ ei, const int* __restrict__ ej,
    const float* __restrict__ u, const float* __restrict__ bconst,
    unsigned short* __restrict__ aggbf)
{
    __shared__ float WL[2][196];
    __shared__ float Dp[2][2][13];
    __shared__ float invL[2][14];
    int wv = threadIdx.x >> 6, lane = threadIdx.x & 63;
    int sp = wv >> 1;          // sample slot 0..1
    int h  = wv & 1;           // channel half 0..1
    int n  = blockIdx.x * 2 + sp;
    size_t base = (size_t)n * K_NODES * C_DIM + h * 256 + lane * 4;

    // load 14 x-rows (4 bf16 each) and convert to fp32
    float xf[K_NODES][4];
    #pragma unroll
    for (int k = 0; k < K_NODES; ++k) {
        uint2 raw = *(const uint2*)(xbf + base + k * C_DIM);
        xf[k][0]=bf2f(raw.x&0xffff); xf[k][1]=bf2f(raw.x>>16);
        xf[k][2]=bf2f(raw.y&0xffff); xf[k][3]=bf2f(raw.y>>16);
    }
    f32x4 uv = *(const f32x4*)(u + h * 256 + lane * 4);

    // per-half D_k partials (wave butterfly reduce)
    #pragma unroll
    for (int k = 0; k < 13; ++k) {
        float p = fabsf(xf[k][0]-xf[13][0])*uv.x + fabsf(xf[k][1]-xf[13][1])*uv.y
                + fabsf(xf[k][2]-xf[13][2])*uv.z + fabsf(xf[k][3]-xf[13][3])*uv.w;
        #pragma unroll
        for (int off = 1; off < 64; off <<= 1) p += __shfl_xor(p, off, 64);
        if (lane == 0) Dp[sp][h][k] = p;
    }
    __syncthreads();

    if (h == 0) {
        // even wave: gate the 156 edge entries (edges lane and lane+64)
        for (int e = lane; e < N_EDGE; e += 64) {
            int ii = ei[e], jj = ej[e];
            float Di = Dp[sp][0][ii] + Dp[sp][1][ii];
            float Dj = Dp[sp][0][jj] + Dp[sp][1][jj];
            float z = 4.0f * (15.f * (Di - Dj) + *bconst);
            float a = 1.f / (1.f + expf(-z));
            WL[sp][ii * K_NODES + jj] = adj[ii * K_NODES + jj] * (2.f * a);
            WL[sp][jj * K_NODES + ii] = adj[jj * K_NODES + ii] * (2.f * (1.f - a));
        }
    } else {
        // odd wave: non-edge entries (i==j or i==13 or j==13) keep adj value
        for (int idx = lane; idx < K_NODES * K_NODES; idx += 64) {
            int i = idx / K_NODES, j = idx - i * K_NODES;
            if (i == j || i == 13 || j == 13) WL[sp][idx] = adj[idx];
        }
    }
    __syncthreads();
    if (h == 0 && lane < K_NODES) {
        float s = 0.f;
        #pragma unroll
        for (int j = 0; j < K_NODES; ++j) s += fabsf(WL[sp][lane * K_NODES + j]);
        invL[sp][lane] = 1.f / fmaxf(s, 1e-12f);
    }
    __syncthreads();

    // agg[i][c] = inv[i] * sum_j W[i][j] * x[j][c]  (each wave: its 256-ch half)
    #pragma unroll
    for (int i = 0; i < K_NODES; ++i) {
        float s0=0.f,s1=0.f,s2=0.f,s3=0.f;
        #pragma unroll
        for (int j = 0; j < K_NODES; ++j) {
            float w = WL[sp][i * K_NODES + j];
            s0 += w*xf[j][0]; s1 += w*xf[j][1]; s2 += w*xf[j][2]; s3 += w*xf[j][3];
        }
        float wi = invL[sp][i];
        uint2 r;
        r.x = (unsigned int)f2bf(s0*wi) | ((unsigned int)f2bf(s1*wi) << 16);
        r.y = (unsigned int)f2bf(s2*wi) | ((unsigned int)f2bf(s3*wi) << 16);
        *(uint2*)(aggbf + base + i * C_DIM) = r;
    }
}

// ---------------- Kernel 4: fused GEMM: relu(agg@Wm^T) + x@Wo^T ------------
// 128x128 tile, BK=64, global_load_lds width=16, XOR-swizzled LDS:
// LDS chunk (row, pc) holds logical 16B chunk lc = pc ^ (row&7).
#define TM 128
#define TN 128
#define BK 64

__global__ __launch_bounds__(256) void gemm_fused(
    const unsigned short* __restrict__ Aagg, const unsigned short* __restrict__ Axin,
    const unsigned short* __restrict__ Bwm,  const unsigned short* __restrict__ Bwo,
    float* __restrict__ out)
{
    __shared__ unsigned short lA[TM * BK];   // 16 KB
    __shared__ unsigned short lB[TN * BK];   // 16 KB
    int tid  = threadIdx.x;
    int lane = tid & 63;
    int wave = tid >> 6;
    int wr = wave >> 1, wc = wave & 1;
    int bm = blockIdx.x * TM;
    int bn = blockIdx.y * TN;

    f32x4 acc[4][4];
    #pragma unroll
    for (int i = 0; i < 4; ++i)
        #pragma unroll
        for (int j = 0; j < 4; ++j) acc[i][j] = (f32x4){0.f, 0.f, 0.f, 0.f};

    int lrow = lane & 15;
    int xorv = lane & 7;
    int srow  = tid >> 3;
    int lcu   = ((tid & 7) ^ (srow & 7)) * 8;

    #pragma unroll
    for (int pass = 0; pass < 2; ++pass) {
        const unsigned short* A = pass ? Axin : Aagg;
        const unsigned short* B = pass ? Bwo  : Bwm;
        for (int kb = 0; kb < C_DIM; kb += BK) {
            __syncthreads();
            #pragma unroll
            for (int it = 0; it < 4; ++it) {
                int row = it * 32 + srow;
                async16(A + (size_t)(bm + row) * C_DIM + kb + lcu,
                        &lA[(size_t)(it * 256 + wave * 64) * 8]);
                async16(B + (size_t)(bn + row) * C_DIM + kb + lcu,
                        &lB[(size_t)(it * 256 + wave * 64) * 8]);
            }
            __syncthreads();
            #pragma unroll
            for (int ks = 0; ks < 2; ++ks) {
                int pchunk = ((ks * 4 + (lane >> 4)) ^ xorv) * 8;
                bf16x8 af[4], bfr[4];
                #pragma unroll
                for (int i = 0; i < 4; ++i)
                    af[i] = *(const bf16x8*)&lA[(wr * 64 + i * 16 + lrow) * BK + pchunk];
                #pragma unroll
                for (int j = 0; j < 4; ++j)
                    bfr[j] = *(const bf16x8*)&lB[(wc * 64 + j * 16 + lrow) * BK + pchunk];
                #pragma unroll
                for (int i = 0; i < 4; ++i)
                    #pragma unroll
                    for (int j = 0; j < 4; ++j)
                        acc[i][j] = __builtin_amdgcn_mfma_f32_16x16x32_bf16(
                            af[i], bfr[j], acc[i][j], 0, 0, 0);
            }
        }
        if (pass == 0) {
            #pragma unroll
            for (int i = 0; i < 4; ++i)
                #pragma unroll
                for (int j = 0; j < 4; ++j)
                    #pragma unroll
                    for (int r = 0; r < 4; ++r)
                        acc[i][j][r] = fmaxf(acc[i][j][r], 0.f);
        }
    }

    int orow0 = bm + wr * 64 + (lane >> 4) * 4;
    int ocol0 = bn + wc * 64 + (lane & 15);
    #pragma unroll
    for (int i = 0; i < 4; ++i)
        #pragma unroll
        for (int j = 0; j < 4; ++j)
            #pragma unroll
            for (int r = 0; r < 4; ++r)
                out[(size_t)(orow0 + i * 16 + r) * OUT_DIM + (ocol0 + j * 16)] = acc[i][j][r];
}

extern "C" void kernel_launch(void* const* d_in, const int* in_sizes, int n_in,
                              void* d_out, int out_size, void* d_ws, size_t ws_size,
                              hipStream_t stream)
{
    const float* x     = (const float*)d_in[0];
    const float* adj   = (const float*)d_in[1];
    const int*   ei    = (const int*)d_in[2];
    const int*   ej    = (const int*)d_in[3];
    const float* gamma = (const float*)d_in[4];
    const float* beta  = (const float*)d_in[5];
    const float* wdir  = (const float*)d_in[6];
    const float* Wm    = (const float*)d_in[7];
    const float* Wo    = (const float*)d_in[8];
    float* out = (float*)d_out;

    int N = in_sizes[0] / (K_NODES * C_DIM);   // 2048
    int M = N * K_NODES;                        // 28672

    float* ws_f   = (float*)d_ws;
    float* u      = ws_f + 1024;               // [512]
    float* bconst = ws_f + 1536;               // [1]
    float* part   = ws_f + 2048;               // [256*1024]
    char*  wsb    = (char*)d_ws;
    size_t off    = (size_t)(2048 + 256 * 1024) * sizeof(float);
    unsigned short* wmbf  = (unsigned short*)(wsb + off);  off += (size_t)OUT_DIM * C_DIM * 2;
    unsigned short* wobf  = (unsigned short*)(wsb + off);  off += (size_t)OUT_DIM * C_DIM * 2;
    unsigned short* xbf   = (unsigned short*)(wsb + off);  off += (size_t)M * C_DIM * 2;
    unsigned short* aggbf = (unsigned short*)(wsb + off);

    float inv_ne = 1.0f / ((float)N * (float)N_EDGE);

    hipLaunchKernelGGL(stats_partial, dim3(N / 8), dim3(1024), 0, stream,
                       x, part, xbf, Wm, Wo, wmbf, wobf);
    hipLaunchKernelGGL(finalize_stats, dim3(1), dim3(1024), 0, stream,
                       part, inv_ne, gamma, beta, wdir, u, bconst);
    hipLaunchKernelGGL(fuse_graph, dim3(N / 2), dim3(256), 0, stream,
                       xbf, adj, ei, ej, u, bconst, aggbf);
    hipLaunchKernelGGL(gemm_fused, dim3(M / TM, OUT_DIM / TN), dim3(256), 0, stream,
                       aggbf, xbf, wmbf, wobf, out);
}